// Round 1
// baseline (219.433 us; speedup 1.0000x reference)
//
#include <hip/hip_runtime.h>

typedef unsigned short u16;
typedef float f32x4 __attribute__((ext_vector_type(4)));
typedef __bf16 bf16x8 __attribute__((ext_vector_type(8)));

#define DEV static __device__ __forceinline__

constexpr int kB = 2;
constexpr int kL = 2048;
constexpr int kD = 1024;
constexpr int kH = 16;
constexpr int kP = 64;
constexpr int kM = kB * kL;  // 4096 tokens

DEV u16 f2bf(float x) {
  union { float f; unsigned u; } v;
  v.f = x;
  unsigned r = v.u + 0x7fffu + ((v.u >> 16) & 1u);  // round-to-nearest-even
  return (u16)(r >> 16);
}

DEV void gload16(const void* g, void* l) {
  __builtin_amdgcn_global_load_lds(
      (const __attribute__((address_space(1))) unsigned int*)g,
      (__attribute__((address_space(3))) unsigned int*)l, 16, 0, 0);
}

// ---------------------------------------------------------------- convert
__global__ void cvt_kernel(const float* __restrict__ src, u16* __restrict__ dst, int n4) {
  int i = blockIdx.x * blockDim.x + threadIdx.x;
  if (i >= n4) return;
  float4 v = reinterpret_cast<const float4*>(src)[i];
  uint2 o;
  o.x = (unsigned)f2bf(v.x) | ((unsigned)f2bf(v.y) << 16);
  o.y = (unsigned)f2bf(v.z) | ((unsigned)f2bf(v.w) << 16);
  reinterpret_cast<uint2*>(dst)[i] = o;
}

// ---------------------------------------------------------------- GEMM core
// C[m,n] = sum_k A[m,k] * W[n,k]   (both row-major bf16, K = kD)
// 128x128 tile, BK=32, 4 waves; wave computes 64x64 (4x4 frags of 16x16x32).
DEV void gemm_tile(const u16* __restrict__ A, const u16* __restrict__ W,
                   int m0, int n0, u16* As, u16* Bs, f32x4 acc[4][4]) {
  const int tid = threadIdx.x;
  const int w = tid >> 6, lane = tid & 63;
  const int wr = w >> 1, wc = w & 1;
  const int g = lane >> 4, c = lane & 15;
  const int srow = lane >> 2;           // 0..15 (row within 16-row stripe)
  const int skoff = (lane & 3) * 8;     // k element offset 0/8/16/24

  for (int k0 = 0; k0 < kD; k0 += 32) {
    __syncthreads();  // previous compute done before overwriting LDS
#pragma unroll
    for (int j = 0; j < 2; ++j) {
      const u16* ga = A + (size_t)(m0 + w * 32 + j * 16 + srow) * kD + k0 + skoff;
      gload16(ga, As + (w * 32 + j * 16) * 32);
      const u16* gb = W + (size_t)(n0 + w * 32 + j * 16 + srow) * kD + k0 + skoff;
      gload16(gb, Bs + (w * 32 + j * 16) * 32);
    }
    __syncthreads();  // drains vmcnt(0): staged data visible

    bf16x8 af[4], bfr[4];
#pragma unroll
    for (int f = 0; f < 4; ++f) {
      af[f]  = *reinterpret_cast<const bf16x8*>(As + (wr * 64 + f * 16 + c) * 32 + g * 8);
      bfr[f] = *reinterpret_cast<const bf16x8*>(Bs + (wc * 64 + f * 16 + c) * 32 + g * 8);
    }
#pragma unroll
    for (int fi = 0; fi < 4; ++fi)
#pragma unroll
      for (int fj = 0; fj < 4; ++fj)
        acc[fi][fj] = __builtin_amdgcn_mfma_f32_16x16x32_bf16(af[fi], bfr[fj], acc[fi][fj], 0, 0, 0);
  }
}

// ---------------------------------------------------------------- QKV GEMM
// grid (32, 24): y<8 -> Q, y<16 -> K, else V. Q,K -> bf16 [B,H,L,P]; V -> bf16 [B,H,P,L].
__global__ __launch_bounds__(256) void qkv_kernel(
    const u16* __restrict__ xb,
    const u16* __restrict__ wq, const u16* __restrict__ wk, const u16* __restrict__ wv,
    const float* __restrict__ bq, const float* __restrict__ bk, const float* __restrict__ bv,
    u16* __restrict__ qb, u16* __restrict__ kb, u16* __restrict__ vtb) {
  __shared__ u16 As[128 * 32], Bs[128 * 32];
  const int mb = blockIdx.x, nb = blockIdx.y;
  const int sel = nb >> 3;
  const int m0 = mb * 128, n0 = (nb & 7) * 128;
  const u16* W = sel == 0 ? wq : (sel == 1 ? wk : wv);
  const float* bias = sel == 0 ? bq : (sel == 1 ? bk : bv);

  f32x4 acc[4][4];
#pragma unroll
  for (int i = 0; i < 4; ++i)
#pragma unroll
    for (int j = 0; j < 4; ++j) acc[i][j] = f32x4{0.f, 0.f, 0.f, 0.f};

  gemm_tile(xb, W, m0, n0, As, Bs, acc);

  const int lane = threadIdx.x & 63, w = threadIdx.x >> 6;
  const int wr = w >> 1, wc = w & 1, g = lane >> 4, c = lane & 15;
  u16* dst = sel == 0 ? qb : (sel == 1 ? kb : vtb);
  const bool transposed = (sel == 2);

#pragma unroll
  for (int fj = 0; fj < 4; ++fj) {
    int n = n0 + wc * 64 + fj * 16 + c;
    float bv_ = bias[n];
    int h = n >> 6, p = n & 63;
#pragma unroll
    for (int fi = 0; fi < 4; ++fi) {
#pragma unroll
      for (int r = 0; r < 4; ++r) {
        int m = m0 + wr * 64 + fi * 16 + g * 4 + r;
        int b = m >> 11, l = m & 2047;
        float val = acc[fi][fj][r] + bv_;
        size_t idx = transposed
                         ? (((size_t)(b * kH + h)) * kP + p) * kL + l
                         : (((size_t)(b * kH + h)) * kL + l) * kP + p;
        dst[idx] = f2bf(val);
      }
    }
  }
}

// ---------------------------------------------------------------- output GEMM
__global__ __launch_bounds__(256) void out_kernel(
    const u16* __restrict__ ob, const u16* __restrict__ wo,
    const float* __restrict__ bo, float* __restrict__ out) {
  __shared__ u16 As[128 * 32], Bs[128 * 32];
  const int m0 = blockIdx.x * 128, n0 = blockIdx.y * 128;
  f32x4 acc[4][4];
#pragma unroll
  for (int i = 0; i < 4; ++i)
#pragma unroll
    for (int j = 0; j < 4; ++j) acc[i][j] = f32x4{0.f, 0.f, 0.f, 0.f};

  gemm_tile(ob, wo, m0, n0, As, Bs, acc);

  const int lane = threadIdx.x & 63, w = threadIdx.x >> 6;
  const int wr = w >> 1, wc = w & 1, g = lane >> 4, c = lane & 15;
#pragma unroll
  for (int fj = 0; fj < 4; ++fj) {
    int n = n0 + wc * 64 + fj * 16 + c;
    float bv_ = bo[n];
#pragma unroll
    for (int fi = 0; fi < 4; ++fi) {
#pragma unroll
      for (int r = 0; r < 4; ++r) {
        int m = m0 + wr * 64 + fi * 16 + g * 4 + r;
        out[(size_t)m * kD + n] = acc[fi][fj][r] + bv_;
      }
    }
  }
}

// ---------------------------------------------------------------- flash attention
// grid (L/128, H, B); 4 waves, 32 queries/wave. Softmax over keys (online).
// Q,K: [B,H,L,P] bf16. Vt: [B,H,P,L] bf16. Out: o_buf [B,L,H,P] bf16.
__global__ __launch_bounds__(256) void attn_kernel(
    const u16* __restrict__ qb, const u16* __restrict__ kb,
    const u16* __restrict__ vtb, u16* __restrict__ ob) {
  __shared__ u16 plds[4][32][40];  // per-wave P^T tile [m 32][l 32], stride 40 (pad)
  const int qblk = blockIdx.x;
  const int h = blockIdx.y;
  const int b = blockIdx.z;
  const int tid = threadIdx.x, w = tid >> 6, lane = tid & 63;
  const int g = lane >> 4, c = lane & 15;
  const size_t hoff = ((size_t)(b * kH + h)) * kL * kP;
  const u16* Q = qb + hoff;
  const u16* K = kb + hoff;
  const u16* Vt = vtb + hoff;
  const int m0 = qblk * 128 + w * 32;

  // Q fragments: [mt][p-chunk], hoisted
  bf16x8 qf[2][2];
#pragma unroll
  for (int mt = 0; mt < 2; ++mt)
#pragma unroll
    for (int ch = 0; ch < 2; ++ch)
      qf[mt][ch] = *reinterpret_cast<const bf16x8*>(
          Q + (size_t)(m0 + mt * 16 + c) * kP + ch * 32 + g * 8);

  f32x4 oacc[2][4];
#pragma unroll
  for (int mt = 0; mt < 2; ++mt)
#pragma unroll
    for (int pt = 0; pt < 4; ++pt) oacc[mt][pt] = f32x4{0.f, 0.f, 0.f, 0.f};
  float Mrun[2] = {-1e30f, -1e30f};
  float Srun[2] = {0.f, 0.f};

  for (int l0 = 0; l0 < kL; l0 += 32) {
    // S tiles: s[lt][mt], S[l][m] fragment (row=l part, col=m)
    f32x4 s[2][2];
#pragma unroll
    for (int lt = 0; lt < 2; ++lt) {
      bf16x8 kf0 = *reinterpret_cast<const bf16x8*>(
          K + (size_t)(l0 + lt * 16 + c) * kP + g * 8);
      bf16x8 kf1 = *reinterpret_cast<const bf16x8*>(
          K + (size_t)(l0 + lt * 16 + c) * kP + 32 + g * 8);
#pragma unroll
      for (int mt = 0; mt < 2; ++mt) {
        f32x4 z = f32x4{0.f, 0.f, 0.f, 0.f};
        z = __builtin_amdgcn_mfma_f32_16x16x32_bf16(kf0, qf[mt][0], z, 0, 0, 0);
        z = __builtin_amdgcn_mfma_f32_16x16x32_bf16(kf1, qf[mt][1], z, 0, 0, 0);
        s[lt][mt] = z;
      }
    }
    // online softmax per query column (column m = lane&15 within mt tile)
#pragma unroll
    for (int mt = 0; mt < 2; ++mt) {
      float cmax = -1e30f;
#pragma unroll
      for (int lt = 0; lt < 2; ++lt)
#pragma unroll
        for (int r = 0; r < 4; ++r) {
          s[lt][mt][r] *= 0.125f;  // 1/sqrt(P)
          cmax = fmaxf(cmax, s[lt][mt][r]);
        }
      cmax = fmaxf(cmax, __shfl_xor(cmax, 16, 64));
      cmax = fmaxf(cmax, __shfl_xor(cmax, 32, 64));
      float Mn = fmaxf(Mrun[mt], cmax);
      float fsc = __expf(Mrun[mt] - Mn);
      Mrun[mt] = Mn;
      float tsum = 0.f;
#pragma unroll
      for (int lt = 0; lt < 2; ++lt)
#pragma unroll
        for (int r = 0; r < 4; ++r) {
          float pv = __expf(s[lt][mt][r] - Mn);
          s[lt][mt][r] = pv;
          tsum += pv;
        }
      tsum += __shfl_xor(tsum, 16, 64);
      tsum += __shfl_xor(tsum, 32, 64);
      Srun[mt] = Srun[mt] * fsc + tsum;
      // rescale O rows (row index within tile = g*4+r; factor lives at lane g*4+r)
      float fr[4];
#pragma unroll
      for (int r = 0; r < 4; ++r) fr[r] = __shfl(fsc, g * 4 + r, 64);
#pragma unroll
      for (int pt = 0; pt < 4; ++pt)
#pragma unroll
        for (int r = 0; r < 4; ++r) oacc[mt][pt][r] *= fr[r];
      // write P^T to LDS: row = m (=c), col = l
#pragma unroll
      for (int lt = 0; lt < 2; ++lt)
#pragma unroll
        for (int r = 0; r < 4; ++r)
          plds[w][mt * 16 + c][lt * 16 + g * 4 + r] = f2bf(s[lt][mt][r]);
    }
    // PV: A-frag = P^T[m][l-chunk] from LDS, B-frag = Vt[p][l-chunk]
    bf16x8 pf[2];
#pragma unroll
    for (int mt = 0; mt < 2; ++mt)
      pf[mt] = *reinterpret_cast<const bf16x8*>(&plds[w][mt * 16 + c][g * 8]);
#pragma unroll
    for (int pt = 0; pt < 4; ++pt) {
      bf16x8 vf = *reinterpret_cast<const bf16x8*>(
          Vt + (size_t)(pt * 16 + c) * kL + l0 + g * 8);
#pragma unroll
      for (int mt = 0; mt < 2; ++mt)
        oacc[mt][pt] = __builtin_amdgcn_mfma_f32_16x16x32_bf16(pf[mt], vf, oacc[mt][pt], 0, 0, 0);
    }
  }

  // normalize and store to o_buf [B, L, H, P]
#pragma unroll
  for (int mt = 0; mt < 2; ++mt) {
    float sr[4];
#pragma unroll
    for (int r = 0; r < 4; ++r) sr[r] = 1.f / __shfl(Srun[mt], g * 4 + r, 64);
#pragma unroll
    for (int pt = 0; pt < 4; ++pt)
#pragma unroll
      for (int r = 0; r < 4; ++r) {
        int m = m0 + mt * 16 + g * 4 + r;
        float val = oacc[mt][pt][r] * sr[r];
        ob[((size_t)(b * kL + m) * kH + h) * kP + pt * 16 + c] = f2bf(val);
      }
  }
}

// ---------------------------------------------------------------- launch
extern "C" void kernel_launch(void* const* d_in, const int* in_sizes, int n_in,
                              void* d_out, int out_size, void* d_ws, size_t ws_size,
                              hipStream_t stream) {
  (void)in_sizes; (void)n_in; (void)out_size; (void)ws_size;
  const float* x  = (const float*)d_in[0];
  const float* Wq = (const float*)d_in[1];
  const float* bq = (const float*)d_in[2];
  const float* Wk = (const float*)d_in[3];
  const float* bk = (const float*)d_in[4];
  const float* Wv = (const float*)d_in[5];
  const float* bv = (const float*)d_in[6];
  const float* Wo = (const float*)d_in[7];
  const float* bo = (const float*)d_in[8];
  float* out = (float*)d_out;

  char* ws = (char*)d_ws;
  u16* xb  = (u16*)(ws);                     // 8 MiB; reused as o_buf after QKV
  u16* wqb = (u16*)(ws + (8u << 20));        // 2 MiB each
  u16* wkb = (u16*)(ws + (10u << 20));
  u16* wvb = (u16*)(ws + (12u << 20));
  u16* wob = (u16*)(ws + (14u << 20));
  u16* qb  = (u16*)(ws + (16u << 20));       // 8 MiB [B,H,L,P]
  u16* kb  = (u16*)(ws + (24u << 20));       // 8 MiB [B,H,L,P]
  u16* vtb = (u16*)(ws + (32u << 20));       // 8 MiB [B,H,P,L]

  cvt_kernel<<<kM * kD / 1024, 256, 0, stream>>>(x, xb, kM * kD / 4);
  cvt_kernel<<<kD * kD / 1024, 256, 0, stream>>>(Wq, wqb, kD * kD / 4);
  cvt_kernel<<<kD * kD / 1024, 256, 0, stream>>>(Wk, wkb, kD * kD / 4);
  cvt_kernel<<<kD * kD / 1024, 256, 0, stream>>>(Wv, wvb, kD * kD / 4);
  cvt_kernel<<<kD * kD / 1024, 256, 0, stream>>>(Wo, wob, kD * kD / 4);

  qkv_kernel<<<dim3(kM / 128, 24), 256, 0, stream>>>(
      xb, wqb, wkb, wvb, bq, bk, bv, qb, kb, vtb);

  attn_kernel<<<dim3(kL / 128, kH, kB), 256, 0, stream>>>(qb, kb, vtb, xb);

  out_kernel<<<dim3(kM / 128, kD / 128), 256, 0, stream>>>(xb, wob, bo, out);
}

// Round 2
// 150.594 us; speedup vs baseline: 1.4571x; 1.4571x over previous
//
#include <hip/hip_runtime.h>

typedef unsigned short u16;
typedef float f32x4 __attribute__((ext_vector_type(4)));
typedef __bf16 bf16x8 __attribute__((ext_vector_type(8)));
typedef __bf16 bf16x4 __attribute__((ext_vector_type(4)));

#define DEV static __device__ __forceinline__

constexpr int kB = 2;
constexpr int kL = 2048;
constexpr int kD = 1024;
constexpr int kH = 16;
constexpr int kP = 64;
constexpr int kM = kB * kL;  // 4096 tokens
constexpr float kQScale = 0.125f * 1.44269504088896f;  // 1/sqrt(P) * log2(e)

DEV u16 f2bf(float x) {
  union { float f; unsigned u; } v;
  v.f = x;
  unsigned r = v.u + 0x7fffu + ((v.u >> 16) & 1u);  // round-to-nearest-even
  return (u16)(r >> 16);
}

DEV void gload16(const void* g, void* l) {
  __builtin_amdgcn_global_load_lds(
      (const __attribute__((address_space(1))) unsigned int*)g,
      (__attribute__((address_space(3))) unsigned int*)l, 16, 0, 0);
}

// ---------------------------------------------------------------- convert
__global__ void cvt_kernel(const float* __restrict__ src, u16* __restrict__ dst, int n4) {
  int i = blockIdx.x * blockDim.x + threadIdx.x;
  if (i >= n4) return;
  float4 v = reinterpret_cast<const float4*>(src)[i];
  uint2 o;
  o.x = (unsigned)f2bf(v.x) | ((unsigned)f2bf(v.y) << 16);
  o.y = (unsigned)f2bf(v.z) | ((unsigned)f2bf(v.w) << 16);
  reinterpret_cast<uint2*>(dst)[i] = o;
}

// ---------------------------------------------------------------- GEMM core
// C[m,n] = sum_k A[m,k] * W[n,k]   (both row-major bf16, K = kD)
DEV void gemm_tile(const u16* __restrict__ A, const u16* __restrict__ W,
                   int m0, int n0, u16* As, u16* Bs, f32x4 acc[4][4]) {
  const int tid = threadIdx.x;
  const int w = tid >> 6, lane = tid & 63;
  const int wr = w >> 1, wc = w & 1;
  const int g = lane >> 4, c = lane & 15;
  const int srow = lane >> 2;
  const int skoff = (lane & 3) * 8;

  for (int k0 = 0; k0 < kD; k0 += 32) {
    __syncthreads();
#pragma unroll
    for (int j = 0; j < 2; ++j) {
      const u16* ga = A + (size_t)(m0 + w * 32 + j * 16 + srow) * kD + k0 + skoff;
      gload16(ga, As + (w * 32 + j * 16) * 32);
      const u16* gb = W + (size_t)(n0 + w * 32 + j * 16 + srow) * kD + k0 + skoff;
      gload16(gb, Bs + (w * 32 + j * 16) * 32);
    }
    __syncthreads();

    bf16x8 af[4], bfr[4];
#pragma unroll
    for (int f = 0; f < 4; ++f) {
      af[f]  = *reinterpret_cast<const bf16x8*>(As + (wr * 64 + f * 16 + c) * 32 + g * 8);
      bfr[f] = *reinterpret_cast<const bf16x8*>(Bs + (wc * 64 + f * 16 + c) * 32 + g * 8);
    }
#pragma unroll
    for (int fi = 0; fi < 4; ++fi)
#pragma unroll
      for (int fj = 0; fj < 4; ++fj)
        acc[fi][fj] = __builtin_amdgcn_mfma_f32_16x16x32_bf16(af[fi], bfr[fj], acc[fi][fj], 0, 0, 0);
  }
}

// ---------------------------------------------------------------- QKV GEMM
// Q scaled by kQScale (softmax runs in exp2 domain). V written transposed.
__global__ __launch_bounds__(256) void qkv_kernel(
    const u16* __restrict__ xb,
    const u16* __restrict__ wq, const u16* __restrict__ wk, const u16* __restrict__ wv,
    const float* __restrict__ bq, const float* __restrict__ bk, const float* __restrict__ bv,
    u16* __restrict__ qb, u16* __restrict__ kb, u16* __restrict__ vtb) {
  __shared__ u16 As[128 * 32], Bs[128 * 32];
  const int mb = blockIdx.x, nb = blockIdx.y;
  const int sel = nb >> 3;
  const int m0 = mb * 128, n0 = (nb & 7) * 128;
  const u16* W = sel == 0 ? wq : (sel == 1 ? wk : wv);
  const float* bias = sel == 0 ? bq : (sel == 1 ? bk : bv);

  f32x4 acc[4][4];
#pragma unroll
  for (int i = 0; i < 4; ++i)
#pragma unroll
    for (int j = 0; j < 4; ++j) acc[i][j] = f32x4{0.f, 0.f, 0.f, 0.f};

  gemm_tile(xb, W, m0, n0, As, Bs, acc);

  const int lane = threadIdx.x & 63, w = threadIdx.x >> 6;
  const int wr = w >> 1, wc = w & 1, g = lane >> 4, c = lane & 15;
  u16* dst = sel == 0 ? qb : (sel == 1 ? kb : vtb);
  const bool transposed = (sel == 2);
  const float scale = (sel == 0) ? kQScale : 1.0f;

#pragma unroll
  for (int fj = 0; fj < 4; ++fj) {
    int n = n0 + wc * 64 + fj * 16 + c;
    float bv_ = bias[n];
    int h = n >> 6, p = n & 63;
#pragma unroll
    for (int fi = 0; fi < 4; ++fi) {
#pragma unroll
      for (int r = 0; r < 4; ++r) {
        int m = m0 + wr * 64 + fi * 16 + g * 4 + r;
        int b = m >> 11, l = m & 2047;
        float val = (acc[fi][fj][r] + bv_) * scale;
        size_t idx = transposed
                         ? (((size_t)(b * kH + h)) * kP + p) * kL + l
                         : (((size_t)(b * kH + h)) * kL + l) * kP + p;
        dst[idx] = f2bf(val);
      }
    }
  }
}

// ---------------------------------------------------------------- output GEMM
__global__ __launch_bounds__(256) void out_kernel(
    const u16* __restrict__ ob, const u16* __restrict__ wo,
    const float* __restrict__ bo, float* __restrict__ out) {
  __shared__ u16 As[128 * 32], Bs[128 * 32];
  const int m0 = blockIdx.x * 128, n0 = blockIdx.y * 128;
  f32x4 acc[4][4];
#pragma unroll
  for (int i = 0; i < 4; ++i)
#pragma unroll
    for (int j = 0; j < 4; ++j) acc[i][j] = f32x4{0.f, 0.f, 0.f, 0.f};

  gemm_tile(ob, wo, m0, n0, As, Bs, acc);

  const int lane = threadIdx.x & 63, w = threadIdx.x >> 6;
  const int wr = w >> 1, wc = w & 1, g = lane >> 4, c = lane & 15;
#pragma unroll
  for (int fj = 0; fj < 4; ++fj) {
    int n = n0 + wc * 64 + fj * 16 + c;
    float bv_ = bo[n];
#pragma unroll
    for (int fi = 0; fi < 4; ++fi) {
#pragma unroll
      for (int r = 0; r < 4; ++r) {
        int m = m0 + wr * 64 + fi * 16 + g * 4 + r;
        out[(size_t)m * kD + n] = acc[fi][fj][r] + bv_;
      }
    }
  }
}

// ---------------------------------------------------------------- flash attention
// grid (L/64, H, B) = 1024 blocks; 4 waves, 16 queries/wave, KVBLK=64.
// K/V staged in LDS (XOR-swizzled), double-buffered, prefetch-before-compute.
// Q pre-scaled by 1/sqrt(P)*log2e -> softmax via exp2, defer-max (THR=8).
__global__ __launch_bounds__(256, 4) void attn_kernel(
    const u16* __restrict__ qb, const u16* __restrict__ kb,
    const u16* __restrict__ vtb, u16* __restrict__ ob) {
  // [buf][K=0/V=1][64 rows][128 bytes, swizzled by byte ^= (row&7)<<4]
  __shared__ __align__(16) char kvs[2][2][8192];
  __shared__ __align__(16) char pts[4][2048];  // per-wave P^T [16][128B swizzled]
  const int tid = threadIdx.x, w = tid >> 6, lane = tid & 63;
  const int g = lane >> 4, c = lane & 15;
  const int h = blockIdx.y, b = blockIdx.z;
  const size_t hoff = ((size_t)(b * kH + h)) * kL * kP;
  const char* Qg = (const char*)(qb + hoff);
  const char* Kg = (const char*)(kb + hoff);
  const char* Vg = (const char*)(vtb + hoff);
  const int q0 = blockIdx.x * 64 + w * 16;

  // staging geometry: wave w covers regions r = w*2+{0,1} of each 8KB tile;
  // lane covers row r*8 + (lane>>3), 16B slot (lane&7), pre-swizzled source.
  const int lrow = lane >> 3;
  const int spb = ((lane & 7) ^ lrow) << 4;  // swizzled byte col within row

  auto stage = [&](int buf, int l0) {
    char* Kd = &kvs[buf][0][0];
    char* Vd = &kvs[buf][1][0];
#pragma unroll
    for (int i = 0; i < 2; ++i) {
      int r = w * 2 + i;
      int row = r * 8 + lrow;
      gload16(Kg + (size_t)(l0 + row) * 128 + spb, Kd + r * 1024);
      gload16(Vg + (size_t)row * (kL * 2) + l0 * 2 + spb, Vd + r * 1024);
    }
  };

  // Q fragments (16 rows x 64), hoisted
  bf16x8 qf[2];
#pragma unroll
  for (int kc = 0; kc < 2; ++kc)
    qf[kc] = *reinterpret_cast<const bf16x8*>(Qg + (size_t)(q0 + c) * 128 + kc * 64 + g * 16);

  f32x4 oacc[4];
#pragma unroll
  for (int pt = 0; pt < 4; ++pt) oacc[pt] = f32x4{0.f, 0.f, 0.f, 0.f};
  float Mrun = 0.f, Srun = 0.f;

  char* myPt = &pts[w][0];
  const int csw = (c & 7) << 4;

  stage(0, 0);
  __syncthreads();

  for (int t = 0; t < kL / 64; ++t) {
    const int cur = t & 1;
    if (t + 1 < kL / 64) stage(cur ^ 1, (t + 1) * 64);
    const char* Ks = &kvs[cur][0][0];
    const char* Vs = &kvs[cur][1][0];

    // QK^T: s[lt] = S[key = lt*16+g*4+r][query = c]  (exp2 domain)
    f32x4 s[4];
#pragma unroll
    for (int lt = 0; lt < 4; ++lt) {
      int row = lt * 16 + c;
      int rsw = (row & 7) << 4;
      bf16x8 k0 = *reinterpret_cast<const bf16x8*>(Ks + row * 128 + ((g * 16) ^ rsw));
      bf16x8 k1 = *reinterpret_cast<const bf16x8*>(Ks + row * 128 + ((64 + g * 16) ^ rsw));
      f32x4 z = f32x4{0.f, 0.f, 0.f, 0.f};
      z = __builtin_amdgcn_mfma_f32_16x16x32_bf16(k0, qf[0], z, 0, 0, 0);
      z = __builtin_amdgcn_mfma_f32_16x16x32_bf16(k1, qf[1], z, 0, 0, 0);
      s[lt] = z;
    }

    // column (=query) max
    float cmax = s[0][0];
#pragma unroll
    for (int lt = 0; lt < 4; ++lt)
#pragma unroll
      for (int r = 0; r < 4; ++r) cmax = fmaxf(cmax, s[lt][r]);
    cmax = fmaxf(cmax, __shfl_xor(cmax, 16, 64));
    cmax = fmaxf(cmax, __shfl_xor(cmax, 32, 64));

    // defer-max: rescale only if some column grew past Mrun + 8
    if (!__all(cmax <= Mrun + 8.f)) {
      float Mn = fmaxf(Mrun, cmax);
      float fsc = exp2f(Mrun - Mn);
      Srun *= fsc;
      float fr[4];
#pragma unroll
      for (int r = 0; r < 4; ++r) fr[r] = __shfl(fsc, g * 4 + r, 64);
#pragma unroll
      for (int pt = 0; pt < 4; ++pt)
#pragma unroll
        for (int r = 0; r < 4; ++r) oacc[pt][r] *= fr[r];
      Mrun = Mn;
    }

    // P = exp2(s - Mrun); pack to bf16 pairs, 8B swizzled stores to P^T
    float tsum = 0.f;
#pragma unroll
    for (int lt = 0; lt < 4; ++lt) {
      bf16x4 pv;
#pragma unroll
      for (int r = 0; r < 4; ++r) {
        float p = exp2f(s[lt][r] - Mrun);
        tsum += p;
        pv[r] = (__bf16)p;
      }
      *reinterpret_cast<bf16x4*>(myPt + c * 128 + ((lt * 32 + g * 8) ^ csw)) = pv;
    }
    tsum += __shfl_xor(tsum, 16, 64);
    tsum += __shfl_xor(tsum, 32, 64);
    Srun += tsum;

    // PV: A = P^T rows (query), B = Vt rows (p); O[query][p]
    bf16x8 pf[2];
#pragma unroll
    for (int lc = 0; lc < 2; ++lc)
      pf[lc] = *reinterpret_cast<const bf16x8*>(myPt + c * 128 + ((lc * 64 + g * 16) ^ csw));
#pragma unroll
    for (int pt = 0; pt < 4; ++pt) {
      int row = pt * 16 + c;
      int rsw = (row & 7) << 4;
      bf16x8 v0 = *reinterpret_cast<const bf16x8*>(Vs + row * 128 + ((g * 16) ^ rsw));
      bf16x8 v1 = *reinterpret_cast<const bf16x8*>(Vs + row * 128 + ((64 + g * 16) ^ rsw));
      oacc[pt] = __builtin_amdgcn_mfma_f32_16x16x32_bf16(pf[0], v0, oacc[pt], 0, 0, 0);
      oacc[pt] = __builtin_amdgcn_mfma_f32_16x16x32_bf16(pf[1], v1, oacc[pt], 0, 0, 0);
    }
    __syncthreads();  // drains prefetch (vmcnt 0) + all waves done with buf[cur]
  }

  // normalize, store to o_buf [B, L, D]
  float rs = 1.f / Srun;
  float fr[4];
#pragma unroll
  for (int r = 0; r < 4; ++r) fr[r] = __shfl(rs, g * 4 + r, 64);
#pragma unroll
  for (int pt = 0; pt < 4; ++pt)
#pragma unroll
    for (int r = 0; r < 4; ++r) {
      int q = q0 + g * 4 + r;
      ob[((size_t)(b * kL + q)) * kD + h * kP + pt * 16 + c] = f2bf(oacc[pt][r] * fr[r]);
    }
}

// ---------------------------------------------------------------- launch
extern "C" void kernel_launch(void* const* d_in, const int* in_sizes, int n_in,
                              void* d_out, int out_size, void* d_ws, size_t ws_size,
                              hipStream_t stream) {
  (void)in_sizes; (void)n_in; (void)out_size; (void)ws_size;
  const float* x  = (const float*)d_in[0];
  const float* Wq = (const float*)d_in[1];
  const float* bq = (const float*)d_in[2];
  const float* Wk = (const float*)d_in[3];
  const float* bk = (const float*)d_in[4];
  const float* Wv = (const float*)d_in[5];
  const float* bv = (const float*)d_in[6];
  const float* Wo = (const float*)d_in[7];
  const float* bo = (const float*)d_in[8];
  float* out = (float*)d_out;

  char* ws = (char*)d_ws;
  u16* xb  = (u16*)(ws);                     // 8 MiB; reused as o_buf after QKV
  u16* wqb = (u16*)(ws + (8u << 20));
  u16* wkb = (u16*)(ws + (10u << 20));
  u16* wvb = (u16*)(ws + (12u << 20));
  u16* wob = (u16*)(ws + (14u << 20));
  u16* qb  = (u16*)(ws + (16u << 20));       // [B,H,L,P] (pre-scaled)
  u16* kb  = (u16*)(ws + (24u << 20));       // [B,H,L,P]
  u16* vtb = (u16*)(ws + (32u << 20));       // [B,H,P,L]

  cvt_kernel<<<kM * kD / 1024, 256, 0, stream>>>(x, xb, kM * kD / 4);
  cvt_kernel<<<kD * kD / 1024, 256, 0, stream>>>(Wq, wqb, kD * kD / 4);
  cvt_kernel<<<kD * kD / 1024, 256, 0, stream>>>(Wk, wkb, kD * kD / 4);
  cvt_kernel<<<kD * kD / 1024, 256, 0, stream>>>(Wv, wvb, kD * kD / 4);
  cvt_kernel<<<kD * kD / 1024, 256, 0, stream>>>(Wo, wob, kD * kD / 4);

  qkv_kernel<<<dim3(kM / 128, 24), 256, 0, stream>>>(
      xb, wqb, wkb, wvb, bq, bk, bv, qb, kb, vtb);

  attn_kernel<<<dim3(kL / 64, kH, kB), 256, 0, stream>>>(qb, kb, vtb, xb);

  out_kernel<<<dim3(kM / 128, kD / 128), 256, 0, stream>>>(xb, wob, bo, out);
}